// Round 1
// baseline (6601.225 us; speedup 1.0000x reference)
//
#include <hip/hip_runtime.h>
#include <math.h>

#define NN 10000
#define NE 60000
#define DD 128
#define NL 15
#define LN_EPS 1e-5f

__device__ __forceinline__ float gelu_exact(float y) {
    return 0.5f * y * (1.0f + erff(y * 0.70710678118654752f));
}

__global__ void count_kernel(const int* __restrict__ ecol, float* __restrict__ cnt) {
    int e = blockIdx.x * blockDim.x + threadIdx.x;
    if (e < NE) atomicAdd(&cnt[ecol[e]], 1.0f);
}

// ---------------- Edge MLP: 16 edges per block, 256 threads ----------------
// in  = [x[row], x[col], ea]  (384)
// h   = gelu(LN(in @ W1 + b1))  (256)
// o   = LN(h @ W2 + b2)         (128)
// ea += o ; agg[col] += ea (atomic)
__global__ __launch_bounds__(256)
void edge_mlp_kernel(const float* __restrict__ x,
                     const int* __restrict__ erow, const int* __restrict__ ecol,
                     float* __restrict__ ea, float* __restrict__ agg,
                     const float* __restrict__ W1, const float* __restrict__ b1,
                     const float* __restrict__ g1, const float* __restrict__ bt1,
                     const float* __restrict__ W2, const float* __restrict__ b2,
                     const float* __restrict__ g2, const float* __restrict__ bt2)
{
    __shared__ float Ain[16][384];
    __shared__ float H[16][256];
    __shared__ float red[2][16][16];
    __shared__ float mu_s[16], rs_s[16];

    const int tid = threadIdx.x;
    const int e0 = blockIdx.x * 16;

    // gather input tile
    for (int idx = tid; idx < 16 * 384; idx += 256) {
        const int r = idx / 384;
        const int p = idx - r * 384;
        const int e = e0 + r;
        float v = 0.0f;
        if (e < NE) {
            if (p < 128)      v = x[erow[e] * DD + p];
            else if (p < 256) v = x[ecol[e] * DD + (p - 128)];
            else              v = ea[e * DD + (p - 256)];
        }
        Ain[r][p] = v;
    }
    __syncthreads();

    // ---- stage 1: H = A(16x384) @ W1(384x256) + b1, col = tid ----
    {
        const int c = tid;
        float acc[16];
        const float bias = b1[c];
        #pragma unroll
        for (int m = 0; m < 16; ++m) acc[m] = bias;
        for (int k = 0; k < 384; k += 4) {
            const float w0 = W1[(k + 0) * 256 + c];
            const float w1 = W1[(k + 1) * 256 + c];
            const float w2 = W1[(k + 2) * 256 + c];
            const float w3 = W1[(k + 3) * 256 + c];
            #pragma unroll
            for (int m = 0; m < 16; ++m) {
                const float4 a = *(const float4*)&Ain[m][k];
                acc[m] = fmaf(a.x, w0, acc[m]);
                acc[m] = fmaf(a.y, w1, acc[m]);
                acc[m] = fmaf(a.z, w2, acc[m]);
                acc[m] = fmaf(a.w, w3, acc[m]);
            }
        }
        #pragma unroll
        for (int m = 0; m < 16; ++m) H[m][c] = acc[m];
    }
    __syncthreads();
    // LN1 stats over 256
    {
        const int m = tid >> 4, j = tid & 15;
        float s = 0.f, sq = 0.f;
        #pragma unroll
        for (int u = 0; u < 16; ++u) {
            const float v = H[m][j + 16 * u];
            s += v; sq += v * v;
        }
        red[0][m][j] = s; red[1][m][j] = sq;
    }
    __syncthreads();
    if (tid < 16) {
        float s = 0.f, sq = 0.f;
        #pragma unroll
        for (int j = 0; j < 16; ++j) { s += red[0][tid][j]; sq += red[1][tid][j]; }
        const float mu = s * (1.0f / 256.0f);
        const float var = sq * (1.0f / 256.0f) - mu * mu;
        mu_s[tid] = mu;
        rs_s[tid] = rsqrtf(var + LN_EPS);
    }
    __syncthreads();
    // apply LN1 + GELU
    {
        const int c = tid;
        const float gc = g1[c], bc = bt1[c];
        #pragma unroll
        for (int m = 0; m < 16; ++m) {
            const float yv = (H[m][c] - mu_s[m]) * rs_s[m] * gc + bc;
            H[m][c] = gelu_exact(yv);
        }
    }
    __syncthreads();

    // ---- stage 2: O = H(16x256) @ W2(256x128) + b2 ----
    float* O = &Ain[0][0];   // 16x128, reuse Ain storage (dead)
    {
        const int c = tid & 127;
        const int half = tid >> 7;
        float acc[8];
        const float bias = b2[c];
        #pragma unroll
        for (int m = 0; m < 8; ++m) acc[m] = bias;
        for (int k = 0; k < 256; k += 4) {
            const float w0 = W2[(k + 0) * 128 + c];
            const float w1 = W2[(k + 1) * 128 + c];
            const float w2 = W2[(k + 2) * 128 + c];
            const float w3 = W2[(k + 3) * 128 + c];
            #pragma unroll
            for (int m = 0; m < 8; ++m) {
                const float4 a = *(const float4*)&H[half * 8 + m][k];
                acc[m] = fmaf(a.x, w0, acc[m]);
                acc[m] = fmaf(a.y, w1, acc[m]);
                acc[m] = fmaf(a.z, w2, acc[m]);
                acc[m] = fmaf(a.w, w3, acc[m]);
            }
        }
        #pragma unroll
        for (int m = 0; m < 8; ++m) O[(half * 8 + m) * 128 + c] = acc[m];
    }
    __syncthreads();
    // LN2 stats over 128
    {
        const int m = tid >> 4, j = tid & 15;
        float s = 0.f, sq = 0.f;
        #pragma unroll
        for (int u = 0; u < 8; ++u) {
            const float v = O[m * 128 + j + 16 * u];
            s += v; sq += v * v;
        }
        red[0][m][j] = s; red[1][m][j] = sq;
    }
    __syncthreads();
    if (tid < 16) {
        float s = 0.f, sq = 0.f;
        #pragma unroll
        for (int j = 0; j < 16; ++j) { s += red[0][tid][j]; sq += red[1][tid][j]; }
        const float mu = s * (1.0f / 128.0f);
        const float var = sq * (1.0f / 128.0f) - mu * mu;
        mu_s[tid] = mu;
        rs_s[tid] = rsqrtf(var + LN_EPS);
    }
    __syncthreads();
    // apply LN2 + residual + atomic aggregate
    {
        const int c = tid & 127;
        const int half = tid >> 7;
        const float gc = g2[c], bc = bt2[c];
        #pragma unroll
        for (int m8 = 0; m8 < 8; ++m8) {
            const int m = half * 8 + m8;
            const int e = e0 + m;
            if (e < NE) {
                const float yv = (O[m * 128 + c] - mu_s[m]) * rs_s[m] * gc + bc;
                const float nv = ea[e * DD + c] + yv;
                ea[e * DD + c] = nv;
                atomicAdd(&agg[ecol[e] * DD + c], nv);
            }
        }
    }
}

// ---------------- Node MLP: 16 nodes per block, 256 threads ----------------
// in = [x[n], agg[n]/cnt[n]] (256) -> gelu(LN(@W1+b1)) (256) -> LN(@W2+b2) (128); x += o
__global__ __launch_bounds__(256)
void node_mlp_kernel(float* __restrict__ x, const float* __restrict__ agg,
                     const float* __restrict__ cnt,
                     const float* __restrict__ W1, const float* __restrict__ b1,
                     const float* __restrict__ g1, const float* __restrict__ bt1,
                     const float* __restrict__ W2, const float* __restrict__ b2,
                     const float* __restrict__ g2, const float* __restrict__ bt2)
{
    __shared__ float Ain[16][256];
    __shared__ float H[16][256];
    __shared__ float red[2][16][16];
    __shared__ float mu_s[16], rs_s[16];

    const int tid = threadIdx.x;
    const int n0 = blockIdx.x * 16;

    for (int idx = tid; idx < 16 * 256; idx += 256) {
        const int r = idx >> 8;
        const int p = idx & 255;
        const int n = n0 + r;
        float v = 0.0f;
        if (n < NN) {
            if (p < 128) v = x[n * DD + p];
            else         v = agg[n * DD + (p - 128)] / fmaxf(cnt[n], 1.0f);
        }
        Ain[r][p] = v;
    }
    __syncthreads();

    // ---- stage 1: H = A(16x256) @ W1(256x256) + b1 ----
    {
        const int c = tid;
        float acc[16];
        const float bias = b1[c];
        #pragma unroll
        for (int m = 0; m < 16; ++m) acc[m] = bias;
        for (int k = 0; k < 256; k += 4) {
            const float w0 = W1[(k + 0) * 256 + c];
            const float w1 = W1[(k + 1) * 256 + c];
            const float w2 = W1[(k + 2) * 256 + c];
            const float w3 = W1[(k + 3) * 256 + c];
            #pragma unroll
            for (int m = 0; m < 16; ++m) {
                const float4 a = *(const float4*)&Ain[m][k];
                acc[m] = fmaf(a.x, w0, acc[m]);
                acc[m] = fmaf(a.y, w1, acc[m]);
                acc[m] = fmaf(a.z, w2, acc[m]);
                acc[m] = fmaf(a.w, w3, acc[m]);
            }
        }
        #pragma unroll
        for (int m = 0; m < 16; ++m) H[m][c] = acc[m];
    }
    __syncthreads();
    {
        const int m = tid >> 4, j = tid & 15;
        float s = 0.f, sq = 0.f;
        #pragma unroll
        for (int u = 0; u < 16; ++u) {
            const float v = H[m][j + 16 * u];
            s += v; sq += v * v;
        }
        red[0][m][j] = s; red[1][m][j] = sq;
    }
    __syncthreads();
    if (tid < 16) {
        float s = 0.f, sq = 0.f;
        #pragma unroll
        for (int j = 0; j < 16; ++j) { s += red[0][tid][j]; sq += red[1][tid][j]; }
        const float mu = s * (1.0f / 256.0f);
        const float var = sq * (1.0f / 256.0f) - mu * mu;
        mu_s[tid] = mu;
        rs_s[tid] = rsqrtf(var + LN_EPS);
    }
    __syncthreads();
    {
        const int c = tid;
        const float gc = g1[c], bc = bt1[c];
        #pragma unroll
        for (int m = 0; m < 16; ++m) {
            const float yv = (H[m][c] - mu_s[m]) * rs_s[m] * gc + bc;
            H[m][c] = gelu_exact(yv);
        }
    }
    __syncthreads();

    // ---- stage 2: O = H(16x256) @ W2(256x128) + b2 ----
    float* O = &Ain[0][0];
    {
        const int c = tid & 127;
        const int half = tid >> 7;
        float acc[8];
        const float bias = b2[c];
        #pragma unroll
        for (int m = 0; m < 8; ++m) acc[m] = bias;
        for (int k = 0; k < 256; k += 4) {
            const float w0 = W2[(k + 0) * 128 + c];
            const float w1 = W2[(k + 1) * 128 + c];
            const float w2 = W2[(k + 2) * 128 + c];
            const float w3 = W2[(k + 3) * 128 + c];
            #pragma unroll
            for (int m = 0; m < 8; ++m) {
                const float4 a = *(const float4*)&H[half * 8 + m][k];
                acc[m] = fmaf(a.x, w0, acc[m]);
                acc[m] = fmaf(a.y, w1, acc[m]);
                acc[m] = fmaf(a.z, w2, acc[m]);
                acc[m] = fmaf(a.w, w3, acc[m]);
            }
        }
        #pragma unroll
        for (int m = 0; m < 8; ++m) O[(half * 8 + m) * 128 + c] = acc[m];
    }
    __syncthreads();
    {
        const int m = tid >> 4, j = tid & 15;
        float s = 0.f, sq = 0.f;
        #pragma unroll
        for (int u = 0; u < 8; ++u) {
            const float v = O[m * 128 + j + 16 * u];
            s += v; sq += v * v;
        }
        red[0][m][j] = s; red[1][m][j] = sq;
    }
    __syncthreads();
    if (tid < 16) {
        float s = 0.f, sq = 0.f;
        #pragma unroll
        for (int j = 0; j < 16; ++j) { s += red[0][tid][j]; sq += red[1][tid][j]; }
        const float mu = s * (1.0f / 128.0f);
        const float var = sq * (1.0f / 128.0f) - mu * mu;
        mu_s[tid] = mu;
        rs_s[tid] = rsqrtf(var + LN_EPS);
    }
    __syncthreads();
    {
        const int c = tid & 127;
        const int half = tid >> 7;
        const float gc = g2[c], bc = bt2[c];
        #pragma unroll
        for (int m8 = 0; m8 < 8; ++m8) {
            const int m = half * 8 + m8;
            const int n = n0 + m;
            if (n < NN) {
                const float yv = (O[m * 128 + c] - mu_s[m]) * rs_s[m] * gc + bc;
                x[n * DD + c] = x[n * DD + c] + yv;
            }
        }
    }
}

extern "C" void kernel_launch(void* const* d_in, const int* in_sizes, int n_in,
                              void* d_out, int out_size, void* d_ws, size_t ws_size,
                              hipStream_t stream) {
    const float* x_in  = (const float*)d_in[0];
    const int*   ei    = (const int*)  d_in[1];
    const float* ea_in = (const float*)d_in[2];
    const float* ew1 = (const float*)d_in[3];
    const float* eb1 = (const float*)d_in[4];
    const float* eg1 = (const float*)d_in[5];
    const float* ebt1= (const float*)d_in[6];
    const float* ew2 = (const float*)d_in[7];
    const float* eb2 = (const float*)d_in[8];
    const float* eg2 = (const float*)d_in[9];
    const float* ebt2= (const float*)d_in[10];
    const float* nw1 = (const float*)d_in[11];
    const float* nb1 = (const float*)d_in[12];
    const float* ng1 = (const float*)d_in[13];
    const float* nbt1= (const float*)d_in[14];
    const float* nw2 = (const float*)d_in[15];
    const float* nb2 = (const float*)d_in[16];
    const float* ng2 = (const float*)d_in[17];
    const float* nbt2= (const float*)d_in[18];

    const int* erow = ei;
    const int* ecol = ei + NE;

    float* xbuf  = (float*)d_out;            // [NN, DD]
    float* eabuf = (float*)d_out + NN * DD;  // [NE, DD]

    float* agg = (float*)d_ws;               // [NN, DD]
    float* cnt = agg + NN * DD;              // [NN]

    // initialize state buffers from inputs
    hipMemcpyAsync(xbuf,  x_in,  (size_t)NN * DD * sizeof(float), hipMemcpyDeviceToDevice, stream);
    hipMemcpyAsync(eabuf, ea_in, (size_t)NE * DD * sizeof(float), hipMemcpyDeviceToDevice, stream);

    // neighbor counts (constant across layers)
    hipMemsetAsync(cnt, 0, NN * sizeof(float), stream);
    count_kernel<<<(NE + 255) / 256, 256, 0, stream>>>(ecol, cnt);

    for (int i = 0; i < NL; ++i) {
        hipMemsetAsync(agg, 0, (size_t)NN * DD * sizeof(float), stream);
        edge_mlp_kernel<<<NE / 16, 256, 0, stream>>>(
            xbuf, erow, ecol, eabuf, agg,
            ew1 + (size_t)i * 384 * 256, eb1 + (size_t)i * 256,
            eg1 + (size_t)i * 256,       ebt1 + (size_t)i * 256,
            ew2 + (size_t)i * 256 * 128, eb2 + (size_t)i * 128,
            eg2 + (size_t)i * 128,       ebt2 + (size_t)i * 128);
        node_mlp_kernel<<<(NN + 15) / 16, 256, 0, stream>>>(
            xbuf, agg, cnt,
            nw1 + (size_t)i * 256 * 256, nb1 + (size_t)i * 256,
            ng1 + (size_t)i * 256,       nbt1 + (size_t)i * 256,
            nw2 + (size_t)i * 256 * 128, nb2 + (size_t)i * 128,
            ng2 + (size_t)i * 128,       nbt2 + (size_t)i * 128);
    }
}

// Round 2
// 3074.567 us; speedup vs baseline: 2.1470x; 2.1470x over previous
//
#include <hip/hip_runtime.h>
#include <math.h>

#define NN 10000
#define NE 60000
#define DD 128
#define NL 15
#define LN_EPS 1e-5f

typedef __attribute__((ext_vector_type(8))) short short8;     // 8 bf16 = 4 VGPRs (MFMA A/B frag)
typedef __attribute__((ext_vector_type(4))) float floatx4;    // MFMA C/D frag
typedef __attribute__((ext_vector_type(4))) unsigned short ushortx4;

__device__ __forceinline__ unsigned short f2bf(float f) {
    unsigned u = __float_as_uint(f);
    u += 0x7fff + ((u >> 16) & 1);   // RNE
    return (unsigned short)(u >> 16);
}
__device__ __forceinline__ float bf2f(unsigned short h) {
    return __uint_as_float(((unsigned)h) << 16);
}
__device__ __forceinline__ float gelu_exact(float y) {
    return 0.5f * y * (1.0f + erff(y * 0.70710678118654752f));
}

// ---- pack fp32 weights [L][K][N] -> bf16 MFMA B-fragment layout ----
// frag (t = n-tile, s = k-step): elem (lane l, j) = W[k=32s+8(l>>4)+j][n=16t+(l&15)]
// dst index = ((layer*T + t)*S + s)*512 + l*8 + j
__global__ void pack_weights(const float* __restrict__ W, unsigned short* __restrict__ P,
                             int Lk, int Kk, int Nk) {
    int tid = blockIdx.x * blockDim.x + threadIdx.x;
    int per_layer = Kk * Nk;
    if (tid >= Lk * per_layer) return;
    int i = tid / per_layer;
    int u = tid - i * per_layer;
    int S = Kk >> 5;
    int t = u / (S * 512);
    int rem = u - t * (S * 512);
    int s = rem >> 9;
    int v = rem & 511;
    int l = v >> 3, j = v & 7;
    int k = (s << 5) + ((l >> 4) << 3) + j;
    int n = (t << 4) + (l & 15);
    P[tid] = f2bf(W[((size_t)i * Kk + k) * Nk + n]);
}

// ---- CSR build (once per launch) ----
__global__ void hist_kernel(const int* __restrict__ ecol, int* __restrict__ cnt) {
    int e = blockIdx.x * blockDim.x + threadIdx.x;
    if (e < NE) atomicAdd(&cnt[ecol[e]], 1);
}

__global__ void scan_kernel(const int* __restrict__ cnt, int* __restrict__ starts,
                            int* __restrict__ cursor, float* __restrict__ cinv) {
    __shared__ int part[256];
    int t = threadIdx.x;
    const int chunk = (NN + 255) / 256;
    int lo = t * chunk;
    int hi = lo + chunk; if (hi > NN) hi = NN;
    int s = 0;
    for (int n = lo; n < hi; ++n) s += cnt[n];
    part[t] = s;
    __syncthreads();
    for (int off = 1; off < 256; off <<= 1) {
        int v = (t >= off) ? part[t - off] : 0;
        __syncthreads();
        part[t] += v;
        __syncthreads();
    }
    int base = part[t] - s;   // exclusive prefix
    for (int n = lo; n < hi; ++n) {
        int c = cnt[n];
        starts[n] = base; cursor[n] = base;
        cinv[n] = 1.0f / (float)(c > 0 ? c : 1);
        base += c;
    }
}

__global__ void fill_kernel(const int* __restrict__ ecol, int* __restrict__ cursor,
                            int* __restrict__ eidx) {
    int e = blockIdx.x * blockDim.x + threadIdx.x;
    if (e < NE) {
        int slot = atomicAdd(&cursor[ecol[e]], 1);
        eidx[slot] = e;
    }
}

// ---- fused MFMA MLP: 64 rows/block, 4 waves ----
// stage1: [64,K1]@[K1,256]+b -> LN -> GELU -> H(bf16, LDS)
// stage2: [64,256]@[256,128]+b -> LN -> target += out
// EDGE: gather [x[row],x[col],ea[e]]; target = ea.
// NODE: gather [x[n], csr_mean(ea)];  target = x (only own rows touched).
template <int K1, int ROWS_TOTAL, bool EDGE>
__global__ __launch_bounds__(256, 3)
void mlp_mfma(const float* xin,
              const int* __restrict__ erow, const int* __restrict__ ecol,
              const int* __restrict__ starts, const int* __restrict__ cnt,
              const float* __restrict__ cinv, const int* __restrict__ eidx,
              float* target, const float* earead,
              const unsigned short* __restrict__ W1p, const unsigned short* __restrict__ W2p,
              const float* __restrict__ b1, const float* __restrict__ g1, const float* __restrict__ bt1,
              const float* __restrict__ b2, const float* __restrict__ g2, const float* __restrict__ bt2)
{
    constexpr int S1 = K1 / 32;      // k-steps stage 1
    __shared__ union {
        unsigned short a1[64 * K1];                                  // stage-1 A tile (bf16, swizzled)
        struct { unsigned short h[64 * 256]; float red[64][4][2]; } p2;  // stage-1 out / stage-2 in
    } sm;

    const int tid  = threadIdx.x;
    const int lane = tid & 63;
    const int w    = tid >> 6;      // wave 0..3
    const int q    = lane >> 4;     // quad
    const int c15  = lane & 15;
    const int r0   = blockIdx.x * 64;

    // ---------------- gather -> A1 (bf16, XOR-swizzled rows) ----------------
    if (EDGE) {
        for (int idx = tid; idx < 64 * (K1 / 4); idx += 256) {
            int r  = idx / (K1 / 4);
            int p4 = (idx - r * (K1 / 4)) << 2;
            int e  = r0 + r;
            float4 v = make_float4(0.f, 0.f, 0.f, 0.f);
            if (e < ROWS_TOTAL) {
                if (p4 < 128)      v = *(const float4*)&xin[(size_t)erow[e] * DD + p4];
                else if (p4 < 256) v = *(const float4*)&xin[(size_t)ecol[e] * DD + (p4 - 128)];
                else               v = *(const float4*)&target[(size_t)e * DD + (p4 - 256)];
            }
            int addr = r * K1 + ((((p4 >> 3) ^ (r & 7)) << 3) | (p4 & 7));
            ushortx4 pk = { f2bf(v.x), f2bf(v.y), f2bf(v.z), f2bf(v.w) };
            *(ushortx4*)&sm.a1[addr] = pk;
        }
    } else {
        for (int idx = tid; idx < 64 * 64; idx += 256) {
            int r  = idx >> 6;
            int p4 = (idx & 63) << 2;
            int n  = r0 + r;
            float4 v = make_float4(0.f, 0.f, 0.f, 0.f);
            if (n < ROWS_TOTAL) {
                if (p4 < 128) {
                    v = *(const float4*)&xin[(size_t)n * DD + p4];
                } else {
                    int c = p4 - 128;
                    int st = starts[n], de = cnt[n];
                    float4 s = make_float4(0.f, 0.f, 0.f, 0.f);
                    for (int i2 = 0; i2 < de; ++i2) {
                        const float4 t4 = *(const float4*)&earead[(size_t)eidx[st + i2] * DD + c];
                        s.x += t4.x; s.y += t4.y; s.z += t4.z; s.w += t4.w;
                    }
                    float ci = cinv[n];
                    v = make_float4(s.x * ci, s.y * ci, s.z * ci, s.w * ci);
                }
            }
            int addr = r * K1 + ((((p4 >> 3) ^ (r & 7)) << 3) | (p4 & 7));
            ushortx4 pk = { f2bf(v.x), f2bf(v.y), f2bf(v.z), f2bf(v.w) };
            *(ushortx4*)&sm.a1[addr] = pk;
        }
    }
    __syncthreads();

    // ---------------- stage 1: waves split N (4 n-tiles each), all 4 m-tiles ----------------
    floatx4 acc[4][4];
    #pragma unroll
    for (int a = 0; a < 4; ++a)
        #pragma unroll
        for (int b = 0; b < 4; ++b)
            acc[a][b] = (floatx4){0.f, 0.f, 0.f, 0.f};

    for (int s = 0; s < S1; ++s) {
        short8 af[4];
        #pragma unroll
        for (int mt = 0; mt < 4; ++mt) {
            int row  = (mt << 4) + c15;                 // A row m = lane&15
            int kgrp = ((s << 2) + q) ^ (row & 7);      // koff>>3, swizzled
            af[mt] = *(const short8*)&sm.a1[row * K1 + (kgrp << 3)];
        }
        short8 bf[4];
        #pragma unroll
        for (int ntl = 0; ntl < 4; ++ntl) {
            int nt = (w << 2) + ntl;
            bf[ntl] = *(const short8*)&W1p[(((nt * S1 + s) << 6) + lane) << 3];
        }
        #pragma unroll
        for (int mt = 0; mt < 4; ++mt)
            #pragma unroll
            for (int ntl = 0; ntl < 4; ++ntl)
                acc[mt][ntl] = __builtin_amdgcn_mfma_f32_16x16x32_bf16(af[mt], bf[ntl], acc[mt][ntl], 0, 0, 0);
    }
    __syncthreads();   // all waves done reading a1 -> safe to overwrite with h

    // ---------------- bias + write raw H (bf16) ----------------
    {
        float b1c[4];
        #pragma unroll
        for (int ntl = 0; ntl < 4; ++ntl) b1c[ntl] = b1[(((w << 2) + ntl) << 4) + c15];
        #pragma unroll
        for (int mt = 0; mt < 4; ++mt)
            #pragma unroll
            for (int ntl = 0; ntl < 4; ++ntl) {
                int col = (((w << 2) + ntl) << 4) + c15;
                #pragma unroll
                for (int r = 0; r < 4; ++r) {
                    int row = (mt << 4) + (q << 2) + r;   // C row = 4*quad + reg
                    float val = acc[mt][ntl][r] + b1c[ntl];
                    int addr = row * 256 + ((((col >> 3) ^ (row & 7)) << 3) | (col & 7));
                    sm.p2.h[addr] = f2bf(val);
                }
            }
    }
    __syncthreads();

    // ---------------- LN1 stats (4 threads per row) ----------------
    {
        int row = tid >> 2, qt = tid & 3;
        float p = 0.f, sq = 0.f;
        #pragma unroll
        for (int g = 0; g < 8; ++g) {
            int col0 = (qt << 6) + (g << 3);
            short8 hv = *(const short8*)&sm.p2.h[row * 256 + ((((col0 >> 3) ^ (row & 7)) << 3))];
            #pragma unroll
            for (int j = 0; j < 8; ++j) {
                float v = bf2f((unsigned short)hv[j]);
                p += v; sq += v * v;
            }
        }
        sm.p2.red[row][qt][0] = p;
        sm.p2.red[row][qt][1] = sq;
    }
    __syncthreads();

    // ---------------- apply LN1 + GELU (in place) ----------------
    {
        int row = tid >> 2, qt = tid & 3;
        float p  = sm.p2.red[row][0][0] + sm.p2.red[row][1][0] + sm.p2.red[row][2][0] + sm.p2.red[row][3][0];
        float sq = sm.p2.red[row][0][1] + sm.p2.red[row][1][1] + sm.p2.red[row][2][1] + sm.p2.red[row][3][1];
        float mu = p * (1.0f / 256.0f);
        float rs = rsqrtf(sq * (1.0f / 256.0f) - mu * mu + LN_EPS);
        #pragma unroll
        for (int g = 0; g < 8; ++g) {
            int col0 = (qt << 6) + (g << 3);
            int addr = row * 256 + ((((col0 >> 3) ^ (row & 7)) << 3));
            short8 hv = *(const short8*)&sm.p2.h[addr];
            #pragma unroll
            for (int j = 0; j < 8; ++j) {
                float v = bf2f((unsigned short)hv[j]);
                float y = (v - mu) * rs * g1[col0 + j] + bt1[col0 + j];
                hv[j] = (short)f2bf(gelu_exact(y));
            }
            *(short8*)&sm.p2.h[addr] = hv;
        }
    }
    __syncthreads();

    // ---------------- stage 2: wave w owns rows 16w..16w+15, all 8 n-tiles ----------------
    floatx4 acc2[8];
    #pragma unroll
    for (int nt = 0; nt < 8; ++nt) acc2[nt] = (floatx4){0.f, 0.f, 0.f, 0.f};

    {
        const int row = (w << 4) + c15;
        for (int s = 0; s < 8; ++s) {
            int kgrp = ((s << 2) + q) ^ (row & 7);
            short8 a = *(const short8*)&sm.p2.h[row * 256 + (kgrp << 3)];
            #pragma unroll
            for (int nt = 0; nt < 8; ++nt) {
                short8 b = *(const short8*)&W2p[((((nt << 3) + s) << 6) + lane) << 3];
                acc2[nt] = __builtin_amdgcn_mfma_f32_16x16x32_bf16(a, b, acc2[nt], 0, 0, 0);
            }
        }
    }

    // ---------------- epilogue: bias + LN2 (shfl) + residual store ----------------
    {
        float b2c[8], g2c[8], t2c[8];
        #pragma unroll
        for (int nt = 0; nt < 8; ++nt) {
            int col = (nt << 4) + c15;
            b2c[nt] = b2[col]; g2c[nt] = g2[col]; t2c[nt] = bt2[col];
        }
        #pragma unroll
        for (int nt = 0; nt < 8; ++nt)
            #pragma unroll
            for (int r = 0; r < 4; ++r) acc2[nt][r] += b2c[nt];

        float mu4[4], rs4[4];
        #pragma unroll
        for (int r = 0; r < 4; ++r) {
            float p = 0.f, sq = 0.f;
            #pragma unroll
            for (int nt = 0; nt < 8; ++nt) {
                float v = acc2[nt][r];
                p += v; sq += v * v;
            }
            p += __shfl_xor(p, 1);  sq += __shfl_xor(sq, 1);
            p += __shfl_xor(p, 2);  sq += __shfl_xor(sq, 2);
            p += __shfl_xor(p, 4);  sq += __shfl_xor(sq, 4);
            p += __shfl_xor(p, 8);  sq += __shfl_xor(sq, 8);
            float mu = p * (1.0f / 128.0f);
            mu4[r] = mu;
            rs4[r] = rsqrtf(sq * (1.0f / 128.0f) - mu * mu + LN_EPS);
        }
        #pragma unroll
        for (int r = 0; r < 4; ++r) {
            int rowg = r0 + (w << 4) + (q << 2) + r;
            if (rowg < ROWS_TOTAL) {
                #pragma unroll
                for (int nt = 0; nt < 8; ++nt) {
                    int col = (nt << 4) + c15;
                    float o = (acc2[nt][r] - mu4[r]) * rs4[r] * g2c[nt] + t2c[nt];
                    size_t off = (size_t)rowg * DD + col;
                    target[off] += o;
                }
            }
        }
    }
}

extern "C" void kernel_launch(void* const* d_in, const int* in_sizes, int n_in,
                              void* d_out, int out_size, void* d_ws, size_t ws_size,
                              hipStream_t stream) {
    const float* x_in  = (const float*)d_in[0];
    const int*   ei    = (const int*)  d_in[1];
    const float* ea_in = (const float*)d_in[2];
    const float* ew1 = (const float*)d_in[3];
    const float* eb1 = (const float*)d_in[4];
    const float* eg1 = (const float*)d_in[5];
    const float* ebt1= (const float*)d_in[6];
    const float* ew2 = (const float*)d_in[7];
    const float* eb2 = (const float*)d_in[8];
    const float* eg2 = (const float*)d_in[9];
    const float* ebt2= (const float*)d_in[10];
    const float* nw1 = (const float*)d_in[11];
    const float* nb1 = (const float*)d_in[12];
    const float* ng1 = (const float*)d_in[13];
    const float* nbt1= (const float*)d_in[14];
    const float* nw2 = (const float*)d_in[15];
    const float* nb2 = (const float*)d_in[16];
    const float* ng2 = (const float*)d_in[17];
    const float* nbt2= (const float*)d_in[18];

    const int* erow = ei;
    const int* ecol = ei + NE;

    float* xbuf  = (float*)d_out;            // [NN, DD]
    float* eabuf = (float*)d_out + NN * DD;  // [NE, DD]

    // workspace layout
    unsigned short* ew1p = (unsigned short*)d_ws;                 // 15*384*256
    unsigned short* ew2p = ew1p + NL * 384 * 256;                 // 15*256*128
    unsigned short* nw1p = ew2p + NL * 256 * 128;                 // 15*256*256
    unsigned short* nw2p = nw1p + NL * 256 * 256;                 // 15*256*128
    int*   cnt    = (int*)(nw2p + NL * 256 * 128);
    int*   starts = cnt + NN;
    int*   cursor = starts + NN;
    int*   eidx   = cursor + NN;
    float* cinv   = (float*)(eidx + NE);

    hipMemcpyAsync(xbuf,  x_in,  (size_t)NN * DD * sizeof(float), hipMemcpyDeviceToDevice, stream);
    hipMemcpyAsync(eabuf, ea_in, (size_t)NE * DD * sizeof(float), hipMemcpyDeviceToDevice, stream);

    // CSR build
    hipMemsetAsync(cnt, 0, NN * sizeof(int), stream);
    hist_kernel<<<(NE + 255) / 256, 256, 0, stream>>>(ecol, cnt);
    scan_kernel<<<1, 256, 0, stream>>>(cnt, starts, cursor, cinv);
    fill_kernel<<<(NE + 255) / 256, 256, 0, stream>>>(ecol, cursor, eidx);

    // weight packing (bf16 fragment layout)
    {
        int n1 = NL * 384 * 256, n2 = NL * 256 * 128, n3 = NL * 256 * 256;
        pack_weights<<<(n1 + 255) / 256, 256, 0, stream>>>(ew1, ew1p, NL, 384, 256);
        pack_weights<<<(n2 + 255) / 256, 256, 0, stream>>>(ew2, ew2p, NL, 256, 128);
        pack_weights<<<(n3 + 255) / 256, 256, 0, stream>>>(nw1, nw1p, NL, 256, 256);
        pack_weights<<<(n2 + 255) / 256, 256, 0, stream>>>(nw2, nw2p, NL, 256, 128);
    }

    for (int i = 0; i < NL; ++i) {
        mlp_mfma<384, NE, true><<<(NE + 63) / 64, 256, 0, stream>>>(
            xbuf, erow, ecol, nullptr, nullptr, nullptr, nullptr,
            eabuf, nullptr,
            ew1p + (size_t)i * 384 * 256, ew2p + (size_t)i * 256 * 128,
            eb1 + (size_t)i * 256, eg1 + (size_t)i * 256, ebt1 + (size_t)i * 256,
            eb2 + (size_t)i * 128, eg2 + (size_t)i * 128, ebt2 + (size_t)i * 128);
        mlp_mfma<256, NN, false><<<(NN + 63) / 64, 256, 0, stream>>>(
            xbuf, nullptr, nullptr, starts, cnt, cinv, eidx,
            xbuf, eabuf,
            nw1p + (size_t)i * 256 * 256, nw2p + (size_t)i * 256 * 128,
            nb1 + (size_t)i * 256, ng1 + (size_t)i * 256, nbt1 + (size_t)i * 256,
            nb2 + (size_t)i * 128, ng2 + (size_t)i * 128, nbt2 + (size_t)i * 128);
    }
}

// Round 3
// 2041.369 us; speedup vs baseline: 3.2337x; 1.5061x over previous
//
#include <hip/hip_runtime.h>
#include <math.h>

#define NN 10000
#define NE 60000
#define DD 128
#define NL 15
#define LN_EPS 1e-5f

typedef __attribute__((ext_vector_type(8))) short short8;     // 8 bf16 (MFMA A/B frag)
typedef __attribute__((ext_vector_type(4))) float floatx4;    // MFMA C/D frag
typedef __attribute__((ext_vector_type(4))) unsigned short ushortx4;

__device__ __forceinline__ unsigned short f2bf(float f) {
    unsigned u = __float_as_uint(f);
    u += 0x7fff + ((u >> 16) & 1);   // RNE
    return (unsigned short)(u >> 16);
}
__device__ __forceinline__ float gelu_exact(float y) {
    return 0.5f * y * (1.0f + erff(y * 0.70710678118654752f));
}

// ---- pack fp32 weights [L][K][N] -> bf16 MFMA B-fragment layout ----
// dst index (within layer) = (t*S + s)*512 + l*8 + j ; k=32s+8(l>>4)+j ; n=16t+(l&15)
__device__ __forceinline__ void pack_one(const float* __restrict__ W, unsigned short* __restrict__ P,
                                         int u, int Kk, int Nk) {
    int per_layer = Kk * Nk;
    int i = u / per_layer;
    int v0 = u - i * per_layer;
    int S = Kk >> 5;
    int t = v0 / (S * 512);
    int rem = v0 - t * (S * 512);
    int s = rem >> 9;
    int v = rem & 511;
    int l = v >> 3, j = v & 7;
    int k = (s << 5) + ((l >> 4) << 3) + j;
    int n = (t << 4) + (l & 15);
    P[u] = f2bf(W[((size_t)i * Kk + k) * Nk + n]);
}

#define N_EW1 (NL * 384 * 256)
#define N_EW2 (NL * 256 * 128)
#define N_NW1 (NL * 256 * 256)
#define N_NW2 (NL * 256 * 128)

__global__ void pack_all(const float* __restrict__ ew1, const float* __restrict__ ew2,
                         const float* __restrict__ nw1, const float* __restrict__ nw2,
                         unsigned short* __restrict__ P) {
    int tid = blockIdx.x * blockDim.x + threadIdx.x;
    if (tid < N_EW1) { pack_one(ew1, P, tid, 384, 256); return; }
    tid -= N_EW1;
    if (tid < N_EW2) { pack_one(ew2, P + N_EW1, tid, 256, 128); return; }
    tid -= N_EW2;
    if (tid < N_NW1) { pack_one(nw1, P + N_EW1 + N_EW2, tid, 256, 256); return; }
    tid -= N_NW1;
    if (tid < N_NW2) { pack_one(nw2, P + N_EW1 + N_EW2 + N_NW1, tid, 256, 128); return; }
}

// ---- CSR build (once per launch) ----
__global__ void hist_kernel(const int* __restrict__ ecol, int* __restrict__ cnt) {
    int e = blockIdx.x * blockDim.x + threadIdx.x;
    if (e < NE) atomicAdd(&cnt[ecol[e]], 1);
}

__global__ void scan_kernel(const int* __restrict__ cnt, int* __restrict__ starts,
                            int* __restrict__ cursor, float* __restrict__ cinv) {
    __shared__ int part[256];
    int t = threadIdx.x;
    const int chunk = (NN + 255) / 256;
    int lo = t * chunk;
    int hi = lo + chunk; if (hi > NN) hi = NN;
    int s = 0;
    for (int n = lo; n < hi; ++n) s += cnt[n];
    part[t] = s;
    __syncthreads();
    for (int off = 1; off < 256; off <<= 1) {
        int v = (t >= off) ? part[t - off] : 0;
        __syncthreads();
        part[t] += v;
        __syncthreads();
    }
    int base = part[t] - s;
    for (int n = lo; n < hi; ++n) {
        int c = cnt[n];
        starts[n] = base; cursor[n] = base;
        cinv[n] = 1.0f / (float)(c > 0 ? c : 1);
        base += c;
    }
}

__global__ void fill_kernel(const int* __restrict__ ecol, int* __restrict__ cursor,
                            int* __restrict__ eidx) {
    int e = blockIdx.x * blockDim.x + threadIdx.x;
    if (e < NE) {
        int slot = atomicAdd(&cursor[ecol[e]], 1);
        eidx[slot] = e;
    }
}

// ---- aggregation: one wave per node, lane covers 2 cols (coalesced 512B/edge) ----
__global__ __launch_bounds__(256)
void agg_kernel(const float* __restrict__ ea, const int* __restrict__ starts,
                const int* __restrict__ cnt, const float* __restrict__ cinv,
                const int* __restrict__ eidx, float* __restrict__ agg) {
    int n = blockIdx.x * 4 + (threadIdx.x >> 6);
    if (n >= NN) return;
    int lane = threadIdx.x & 63;
    int st = starts[n], de = cnt[n];
    float sx = 0.f, sy = 0.f;
    for (int i = 0; i < de; ++i) {
        int e = eidx[st + i];
        const float2 v = *(const float2*)&ea[(size_t)e * DD + lane * 2];
        sx += v.x; sy += v.y;
    }
    float ci = cinv[n];
    float2 o; o.x = sx * ci; o.y = sy * ci;
    *(float2*)&agg[(size_t)n * DD + lane * 2] = o;
}

// ---- fused MFMA MLP: 32 rows/block, 4 waves, single H round-trip ----
// stage1: [32,K1]@[K1,256]+b1 -> (in-reg LN stats) -> LN+GELU in reg -> H bf16 LDS (once)
// stage2: [32,256]@[256,128]+b2 -> LN (shfl + wave-pair combine) -> target += out
template <int K1, int ROWS_TOTAL, bool EDGE>
__global__ __launch_bounds__(256, 6)
void mlp_mfma(const float* __restrict__ xin,
              const int* __restrict__ erow, const int* __restrict__ ecol,
              const float* __restrict__ aux,        // NODE: agg (dense fp32)
              float* __restrict__ target,           // EDGE: ea ; NODE: x
              const unsigned short* __restrict__ W1p, const unsigned short* __restrict__ W2p,
              const float* __restrict__ b1, const float* __restrict__ g1, const float* __restrict__ bt1,
              const float* __restrict__ b2, const float* __restrict__ g2, const float* __restrict__ bt2)
{
    constexpr int S1 = K1 / 32;
    constexpr int ROWS = 32;
    __shared__ union {
        unsigned short a1[ROWS * K1];     // gather tile (bf16, XOR-swizzled)
        unsigned short h[ROWS * 256];     // stage-1 activations
    } sm;
    __shared__ float red1[ROWS][8];       // per-wave (p,sq) partials, stage 1
    __shared__ float red2[ROWS][4];       // per-half (p,sq) partials, stage 2

    const int tid  = threadIdx.x;
    const int lane = tid & 63;
    const int w    = tid >> 6;
    const int q    = lane >> 4;
    const int c15  = lane & 15;
    const int r0   = blockIdx.x * ROWS;

    // ---------------- gather -> a1 ----------------
    #pragma unroll
    for (int it = 0; it < (ROWS * (K1 / 4)) / 256; ++it) {
        int idx = tid + it * 256;
        int r   = idx / (K1 / 4);
        int p4  = (idx - r * (K1 / 4)) << 2;
        int row_g = r0 + r;
        float4 v = make_float4(0.f, 0.f, 0.f, 0.f);
        if (EDGE) {
            if (p4 < 128)      v = *(const float4*)&xin[(size_t)erow[row_g] * DD + p4];
            else if (p4 < 256) v = *(const float4*)&xin[(size_t)ecol[row_g] * DD + (p4 - 128)];
            else               v = *(const float4*)&target[(size_t)row_g * DD + (p4 - 256)];
        } else {
            if (ROWS_TOTAL % ROWS == 0 || row_g < ROWS_TOTAL) {
                if (p4 < 128) v = *(const float4*)&xin[(size_t)row_g * DD + p4];
                else          v = *(const float4*)&aux[(size_t)row_g * DD + (p4 - 128)];
            }
        }
        int addr = r * K1 + ((((p4 >> 3) ^ (r & 7)) << 3) | (p4 & 7));
        ushortx4 pk = { f2bf(v.x), f2bf(v.y), f2bf(v.z), f2bf(v.w) };
        *(ushortx4*)&sm.a1[addr] = pk;
    }
    __syncthreads();

    // ---------------- stage 1 MFMA: wave w -> n-tiles 4w..4w+3, m-tiles 0..1 ----------------
    floatx4 acc[2][4];
    #pragma unroll
    for (int mt = 0; mt < 2; ++mt)
        #pragma unroll
        for (int ntl = 0; ntl < 4; ++ntl)
            acc[mt][ntl] = (floatx4){0.f, 0.f, 0.f, 0.f};

    for (int s = 0; s < S1; ++s) {
        short8 af[2];
        #pragma unroll
        for (int mt = 0; mt < 2; ++mt) {
            int row  = (mt << 4) + c15;
            int kgrp = ((s << 2) + q) ^ (row & 7);
            af[mt] = *(const short8*)&sm.a1[row * K1 + (kgrp << 3)];
        }
        #pragma unroll
        for (int ntl = 0; ntl < 4; ++ntl) {
            const short8 bf = *(const short8*)&W1p[((((((w << 2) + ntl) * S1) + s) << 6) + lane) << 3];
            #pragma unroll
            for (int mt = 0; mt < 2; ++mt)
                acc[mt][ntl] = __builtin_amdgcn_mfma_f32_16x16x32_bf16(af[mt], bf, acc[mt][ntl], 0, 0, 0);
        }
    }

    // bias + in-register LN1 partial stats
    float b1c[4], g1c[4], t1c[4];
    #pragma unroll
    for (int ntl = 0; ntl < 4; ++ntl) {
        int col = (((w << 2) + ntl) << 4) + c15;
        b1c[ntl] = b1[col]; g1c[ntl] = g1[col]; t1c[ntl] = bt1[col];
    }
    #pragma unroll
    for (int mt = 0; mt < 2; ++mt)
        #pragma unroll
        for (int r = 0; r < 4; ++r) {
            float p = 0.f, sq = 0.f;
            #pragma unroll
            for (int ntl = 0; ntl < 4; ++ntl) {
                float v = acc[mt][ntl][r] + b1c[ntl];
                acc[mt][ntl][r] = v;
                p += v; sq += v * v;
            }
            p += __shfl_xor(p, 1);  sq += __shfl_xor(sq, 1);
            p += __shfl_xor(p, 2);  sq += __shfl_xor(sq, 2);
            p += __shfl_xor(p, 4);  sq += __shfl_xor(sq, 4);
            p += __shfl_xor(p, 8);  sq += __shfl_xor(sq, 8);
            if (c15 == 0) {
                int row = (mt << 4) + (q << 2) + r;
                red1[row][(w << 1) + 0] = p;
                red1[row][(w << 1) + 1] = sq;
            }
        }
    __syncthreads();   // red1 visible; also: all waves done with a1 -> h writes safe

    // ---------------- apply LN1 + GELU in reg, write H (bf16) once ----------------
    #pragma unroll
    for (int mt = 0; mt < 2; ++mt)
        #pragma unroll
        for (int r = 0; r < 4; ++r) {
            int row = (mt << 4) + (q << 2) + r;
            const float4 p0 = *(const float4*)&red1[row][0];
            const float4 p1 = *(const float4*)&red1[row][4];
            float p  = p0.x + p0.z + p1.x + p1.z;
            float sq = p0.y + p0.w + p1.y + p1.w;
            float mu = p * (1.0f / 256.0f);
            float rs = rsqrtf(sq * (1.0f / 256.0f) - mu * mu + LN_EPS);
            #pragma unroll
            for (int ntl = 0; ntl < 4; ++ntl) {
                int col = (((w << 2) + ntl) << 4) + c15;
                float y = (acc[mt][ntl][r] - mu) * rs * g1c[ntl] + t1c[ntl];
                sm.h[row * 256 + ((((col >> 3) ^ (row & 7)) << 3) | (col & 7))] = f2bf(gelu_exact(y));
            }
        }
    __syncthreads();

    // ---------------- stage 2: wave w -> m-tile (w&1), n-tiles (w>>1)*4.. ----------------
    floatx4 acc2[4];
    #pragma unroll
    for (int j = 0; j < 4; ++j) acc2[j] = (floatx4){0.f, 0.f, 0.f, 0.f};

    const int mrow = ((w & 1) << 4) + c15;
    const int nh   = w >> 1;
    for (int s = 0; s < 8; ++s) {
        int kgrp = ((s << 2) + q) ^ (mrow & 7);
        const short8 a = *(const short8*)&sm.h[mrow * 256 + (kgrp << 3)];
        #pragma unroll
        for (int j = 0; j < 4; ++j) {
            int nt = (nh << 2) + j;
            const short8 b = *(const short8*)&W2p[((((nt << 3) + s) << 6) + lane) << 3];
            acc2[j] = __builtin_amdgcn_mfma_f32_16x16x32_bf16(a, b, acc2[j], 0, 0, 0);
        }
    }

    float b2c[4], g2c[4], t2c[4];
    #pragma unroll
    for (int j = 0; j < 4; ++j) {
        int col = (((nh << 2) + j) << 4) + c15;
        b2c[j] = b2[col]; g2c[j] = g2[col]; t2c[j] = bt2[col];
    }
    #pragma unroll
    for (int r = 0; r < 4; ++r) {
        float p = 0.f, sq = 0.f;
        #pragma unroll
        for (int j = 0; j < 4; ++j) {
            float v = acc2[j][r] + b2c[j];
            acc2[j][r] = v;
            p += v; sq += v * v;
        }
        p += __shfl_xor(p, 1);  sq += __shfl_xor(sq, 1);
        p += __shfl_xor(p, 2);  sq += __shfl_xor(sq, 2);
        p += __shfl_xor(p, 4);  sq += __shfl_xor(sq, 4);
        p += __shfl_xor(p, 8);  sq += __shfl_xor(sq, 8);
        if (c15 == 0) {
            int row = ((w & 1) << 4) + (q << 2) + r;
            red2[row][(nh << 1) + 0] = p;
            red2[row][(nh << 1) + 1] = sq;
        }
    }
    __syncthreads();

    // ---------------- epilogue: LN2 + residual store ----------------
    #pragma unroll
    for (int r = 0; r < 4; ++r) {
        int row = ((w & 1) << 4) + (q << 2) + r;
        const float4 pp = *(const float4*)&red2[row][0];
        float p  = pp.x + pp.z;
        float sq = pp.y + pp.w;
        float mu = p * (1.0f / 128.0f);
        float rs = rsqrtf(sq * (1.0f / 128.0f) - mu * mu + LN_EPS);
        int rowg = r0 + row;
        if (ROWS_TOTAL % ROWS == 0 || rowg < ROWS_TOTAL) {
            #pragma unroll
            for (int j = 0; j < 4; ++j) {
                int col = (((nh << 2) + j) << 4) + c15;
                float o = (acc2[j][r] - mu) * rs * g2c[j] + t2c[j];
                target[(size_t)rowg * DD + col] += o;
            }
        }
    }
}

extern "C" void kernel_launch(void* const* d_in, const int* in_sizes, int n_in,
                              void* d_out, int out_size, void* d_ws, size_t ws_size,
                              hipStream_t stream) {
    const float* x_in  = (const float*)d_in[0];
    const int*   ei    = (const int*)  d_in[1];
    const float* ea_in = (const float*)d_in[2];
    const float* ew1 = (const float*)d_in[3];
    const float* eb1 = (const float*)d_in[4];
    const float* eg1 = (const float*)d_in[5];
    const float* ebt1= (const float*)d_in[6];
    const float* ew2 = (const float*)d_in[7];
    const float* eb2 = (const float*)d_in[8];
    const float* eg2 = (const float*)d_in[9];
    const float* ebt2= (const float*)d_in[10];
    const float* nw1 = (const float*)d_in[11];
    const float* nb1 = (const float*)d_in[12];
    const float* ng1 = (const float*)d_in[13];
    const float* nbt1= (const float*)d_in[14];
    const float* nw2 = (const float*)d_in[15];
    const float* nb2 = (const float*)d_in[16];
    const float* ng2 = (const float*)d_in[17];
    const float* nbt2= (const float*)d_in[18];

    const int* erow = ei;
    const int* ecol = ei + NE;

    float* xbuf  = (float*)d_out;            // [NN, DD]
    float* eabuf = (float*)d_out + NN * DD;  // [NE, DD]

    // workspace layout
    unsigned short* ew1p = (unsigned short*)d_ws;
    unsigned short* ew2p = ew1p + N_EW1;
    unsigned short* nw1p = ew2p + N_EW2;
    unsigned short* nw2p = nw1p + N_NW1;
    int*   cnt    = (int*)(nw2p + N_NW2);
    int*   starts = cnt + NN;
    int*   cursor = starts + NN;
    int*   eidx   = cursor + NN;
    float* cinv   = (float*)(eidx + NE);
    float* agg    = cinv + NN;               // [NN, DD]

    hipMemcpyAsync(xbuf,  x_in,  (size_t)NN * DD * sizeof(float), hipMemcpyDeviceToDevice, stream);
    hipMemcpyAsync(eabuf, ea_in, (size_t)NE * DD * sizeof(float), hipMemcpyDeviceToDevice, stream);

    // CSR build
    hipMemsetAsync(cnt, 0, NN * sizeof(int), stream);
    hist_kernel<<<(NE + 255) / 256, 256, 0, stream>>>(ecol, cnt);
    scan_kernel<<<1, 256, 0, stream>>>(cnt, starts, cursor, cinv);
    fill_kernel<<<(NE + 255) / 256, 256, 0, stream>>>(ecol, cursor, eidx);

    // weight packing (single kernel)
    {
        int ntot = N_EW1 + N_EW2 + N_NW1 + N_NW2;
        pack_all<<<(ntot + 255) / 256, 256, 0, stream>>>(ew1, ew2, nw1, nw2, ew1p);
    }

    for (int i = 0; i < NL; ++i) {
        mlp_mfma<384, NE, true><<<NE / 32, 256, 0, stream>>>(
            xbuf, erow, ecol, nullptr, eabuf,
            ew1p + (size_t)i * 384 * 256, ew2p + (size_t)i * 256 * 128,
            eb1 + (size_t)i * 256, eg1 + (size_t)i * 256, ebt1 + (size_t)i * 256,
            eb2 + (size_t)i * 128, eg2 + (size_t)i * 128, ebt2 + (size_t)i * 128);
        agg_kernel<<<(NN + 3) / 4, 256, 0, stream>>>(eabuf, starts, cnt, cinv, eidx, agg);
        mlp_mfma<256, NN, false><<<(NN + 31) / 32, 256, 0, stream>>>(
            xbuf, nullptr, nullptr, agg, xbuf,
            nw1p + (size_t)i * 256 * 256, nw2p + (size_t)i * 256 * 128,
            nb1 + (size_t)i * 256, ng1 + (size_t)i * 256, nbt1 + (size_t)i * 256,
            nb2 + (size_t)i * 128, ng2 + (size_t)i * 128, nbt2 + (size_t)i * 128);
    }
}

// Round 4
// 1475.033 us; speedup vs baseline: 4.4753x; 1.3839x over previous
//
#include <hip/hip_runtime.h>
#include <math.h>

#define NN 10000
#define NE 60000
#define DD 128
#define NL 15
#define LN_EPS 1e-5f

typedef __attribute__((ext_vector_type(8))) short short8;       // 8 bf16 (MFMA A/B frag)
typedef __attribute__((ext_vector_type(4))) float floatx4;      // MFMA C/D frag
typedef __attribute__((ext_vector_type(4))) unsigned short ushortx4;
typedef __attribute__((ext_vector_type(8))) unsigned short ushortx8;

__device__ __forceinline__ unsigned short f2bf(float f) {
    unsigned u = __float_as_uint(f);
    u += 0x7fff + ((u >> 16) & 1);   // RNE
    return (unsigned short)(u >> 16);
}
// gelu(y) ~= y * sigmoid(1.5957691*y + 0.0713548*y^3)  (tanh-form identity)
__device__ __forceinline__ float gelu_fast(float y) {
    float u = y * y;
    float s2 = y * fmaf(u, 0.07135481283f, 1.59576912161f);
    return y * __builtin_amdgcn_rcpf(1.0f + __expf(-s2));
}

// ---- pack fp32 weights [L][K][N] -> bf16 MFMA B-fragment layout ----
// dst (within layer) = (t*S + s)*512 + l*8 + j ; virtual k = 32s+8(l>>4)+j ; n=16t+(l&15)
// PERM (stage-2 weights, K=256): physical k = ((kv&15)<<4)|(kv>>4)  — matches the
// nibble-swapped H' LDS layout written by stage 1.
__device__ __forceinline__ void pack_one(const float* __restrict__ W, unsigned short* __restrict__ P,
                                         int u, int Kk, int Nk, bool perm) {
    int per_layer = Kk * Nk;
    int i = u / per_layer;
    int v0 = u - i * per_layer;
    int S = Kk >> 5;
    int t = v0 / (S * 512);
    int rem = v0 - t * (S * 512);
    int s = rem >> 9;
    int v = rem & 511;
    int l = v >> 3, j = v & 7;
    int kv = (s << 5) + ((l >> 4) << 3) + j;
    int k = perm ? (((kv & 15) << 4) | (kv >> 4)) : kv;
    int n = (t << 4) + (l & 15);
    P[u] = f2bf(W[((size_t)i * Kk + k) * Nk + n]);
}

#define N_EW1 (NL * 384 * 256)
#define N_EW2 (NL * 256 * 128)
#define N_NW1 (NL * 256 * 256)
#define N_NW2 (NL * 256 * 128)

__global__ void pack_all(const float* __restrict__ ew1, const float* __restrict__ ew2,
                         const float* __restrict__ nw1, const float* __restrict__ nw2,
                         unsigned short* __restrict__ P) {
    int tid = blockIdx.x * blockDim.x + threadIdx.x;
    if (tid < N_EW1) { pack_one(ew1, P, tid, 384, 256, false); return; }
    tid -= N_EW1;
    if (tid < N_EW2) { pack_one(ew2, P + N_EW1, tid, 256, 128, true); return; }
    tid -= N_EW2;
    if (tid < N_NW1) { pack_one(nw1, P + N_EW1 + N_EW2, tid, 256, 256, false); return; }
    tid -= N_NW1;
    if (tid < N_NW2) { pack_one(nw2, P + N_EW1 + N_EW2 + N_NW1, tid, 256, 128, true); return; }
}

// ---- CSR build (once per launch) ----
__global__ void hist_kernel(const int* __restrict__ ecol, int* __restrict__ cnt) {
    int e = blockIdx.x * blockDim.x + threadIdx.x;
    if (e < NE) atomicAdd(&cnt[ecol[e]], 1);
}

__global__ void scan_kernel(const int* __restrict__ cnt, int* __restrict__ starts,
                            int* __restrict__ cursor, float* __restrict__ cinv) {
    __shared__ int part[256];
    int t = threadIdx.x;
    const int chunk = (NN + 255) / 256;
    int lo = t * chunk;
    int hi = lo + chunk; if (hi > NN) hi = NN;
    int s = 0;
    for (int n = lo; n < hi; ++n) s += cnt[n];
    part[t] = s;
    __syncthreads();
    for (int off = 1; off < 256; off <<= 1) {
        int v = (t >= off) ? part[t - off] : 0;
        __syncthreads();
        part[t] += v;
        __syncthreads();
    }
    int base = part[t] - s;
    for (int n = lo; n < hi; ++n) {
        int c = cnt[n];
        starts[n] = base; cursor[n] = base;
        cinv[n] = 1.0f / (float)(c > 0 ? c : 1);
        base += c;
    }
}

__global__ void fill_kernel(const int* __restrict__ ecol, int* __restrict__ cursor,
                            int* __restrict__ eidx) {
    int e = blockIdx.x * blockDim.x + threadIdx.x;
    if (e < NE) {
        int slot = atomicAdd(&cursor[ecol[e]], 1);
        eidx[slot] = e;
    }
}

// ---- aggregation: one wave per node, lane covers 2 cols (coalesced 512B/edge) ----
__global__ __launch_bounds__(256)
void agg_kernel(const float* __restrict__ ea, const int* __restrict__ starts,
                const int* __restrict__ cnt, const float* __restrict__ cinv,
                const int* __restrict__ eidx, float* __restrict__ agg) {
    int n = blockIdx.x * 4 + (threadIdx.x >> 6);
    if (n >= NN) return;
    int lane = threadIdx.x & 63;
    int st = starts[n], de = cnt[n];
    float sx = 0.f, sy = 0.f;
    for (int i = 0; i < de; ++i) {
        int e = eidx[st + i];
        const float2 v = *(const float2*)&ea[(size_t)e * DD + lane * 2];
        sx += v.x; sy += v.y;
    }
    float ci = cinv[n];
    float2 o; o.x = sx * ci; o.y = sy * ci;
    *(float2*)&agg[(size_t)n * DD + lane * 2] = o;
}

// ---- fused MFMA MLP: 32 rows/block, 4 waves, single b64-granular H round-trip ----
template <int K1, int ROWS_TOTAL, bool EDGE>
__global__ __launch_bounds__(256, 6)
void mlp_mfma(const float* __restrict__ xin,
              const int* __restrict__ erow, const int* __restrict__ ecol,
              const float* __restrict__ aux,        // NODE: agg (dense fp32)
              float* __restrict__ target,           // EDGE: ea ; NODE: x
              const unsigned short* __restrict__ W1p, const unsigned short* __restrict__ W2p,
              const float* __restrict__ b1, const float* __restrict__ g1, const float* __restrict__ bt1,
              const float* __restrict__ b2, const float* __restrict__ g2, const float* __restrict__ bt2)
{
    constexpr int S1 = K1 / 32;
    constexpr int ROWS = 32;
    constexpr int P8 = K1 / 8;
    __shared__ union {
        unsigned short a1[ROWS * K1];     // gather tile (bf16, XOR-swizzled groups of 8)
        unsigned short h[ROWS * 256];     // stage-1 activations, nibble-swapped col layout
    } sm;
    __shared__ float red1[ROWS][8];       // per-wave (p,sq) partials, stage 1
    __shared__ float red2[ROWS][4];       // per-half (p,sq) partials, stage 2

    const int tid  = threadIdx.x;
    const int lane = tid & 63;
    const int w    = tid >> 6;
    const int q    = lane >> 4;
    const int c15  = lane & 15;
    const int r0   = blockIdx.x * ROWS;

    // ---------------- gather -> a1 (8 bf16 per iter, one ds_write_b128) ----------------
    #pragma unroll
    for (int it = 0; it < (ROWS * P8) / 256; ++it) {
        int idx = tid + it * 256;
        int r   = idx / P8;
        int p   = (idx - r * P8) << 3;    // 0..K1-8, multiple of 8
        int row_g = r0 + r;
        float4 v0 = make_float4(0.f, 0.f, 0.f, 0.f);
        float4 v1 = v0;
        if (EDGE) {
            const float* src;
            if (p < 128)      src = &xin[(size_t)erow[row_g] * DD + p];
            else if (p < 256) src = &xin[(size_t)ecol[row_g] * DD + (p - 128)];
            else              src = &target[(size_t)row_g * DD + (p - 256)];
            v0 = *(const float4*)src;
            v1 = *(const float4*)(src + 4);
        } else {
            if (ROWS_TOTAL % ROWS == 0 || row_g < ROWS_TOTAL) {
                const float* src = (p < 128) ? &xin[(size_t)row_g * DD + p]
                                             : &aux[(size_t)row_g * DD + (p - 128)];
                v0 = *(const float4*)src;
                v1 = *(const float4*)(src + 4);
            }
        }
        int addr = r * K1 + ((((p >> 3) ^ (r & 7)) << 3));
        ushortx8 pk = { f2bf(v0.x), f2bf(v0.y), f2bf(v0.z), f2bf(v0.w),
                        f2bf(v1.x), f2bf(v1.y), f2bf(v1.z), f2bf(v1.w) };
        *(ushortx8*)&sm.a1[addr] = pk;
    }
    __syncthreads();

    // ---------------- stage 1 MFMA: wave w -> n-tiles 4w..4w+3, m-tiles 0..1 ----------------
    floatx4 acc[2][4];
    #pragma unroll
    for (int mt = 0; mt < 2; ++mt)
        #pragma unroll
        for (int ntl = 0; ntl < 4; ++ntl)
            acc[mt][ntl] = (floatx4){0.f, 0.f, 0.f, 0.f};

    for (int s = 0; s < S1; ++s) {
        short8 af[2];
        #pragma unroll
        for (int mt = 0; mt < 2; ++mt) {
            int row  = (mt << 4) + c15;
            int kgrp = ((s << 2) + q) ^ (row & 7);
            af[mt] = *(const short8*)&sm.a1[row * K1 + (kgrp << 3)];
        }
        #pragma unroll
        for (int ntl = 0; ntl < 4; ++ntl) {
            const short8 bf = *(const short8*)&W1p[((((((w << 2) + ntl) * S1) + s) << 6) + lane) << 3];
            #pragma unroll
            for (int mt = 0; mt < 2; ++mt)
                acc[mt][ntl] = __builtin_amdgcn_mfma_f32_16x16x32_bf16(af[mt], bf, acc[mt][ntl], 0, 0, 0);
        }
    }

    // bias + in-register LN1 partial stats
    float b1c[4], g1c[4], t1c[4];
    #pragma unroll
    for (int ntl = 0; ntl < 4; ++ntl) {
        int col = (((w << 2) + ntl) << 4) + c15;
        b1c[ntl] = b1[col]; g1c[ntl] = g1[col]; t1c[ntl] = bt1[col];
    }
    #pragma unroll
    for (int mt = 0; mt < 2; ++mt)
        #pragma unroll
        for (int r = 0; r < 4; ++r) {
            float p = 0.f, sq = 0.f;
            #pragma unroll
            for (int ntl = 0; ntl < 4; ++ntl) {
                float v = acc[mt][ntl][r] + b1c[ntl];
                acc[mt][ntl][r] = v;
                p += v; sq += v * v;
            }
            p += __shfl_xor(p, 1);  sq += __shfl_xor(sq, 1);
            p += __shfl_xor(p, 2);  sq += __shfl_xor(sq, 2);
            p += __shfl_xor(p, 4);  sq += __shfl_xor(sq, 4);
            p += __shfl_xor(p, 8);  sq += __shfl_xor(sq, 8);
            if (c15 == 0) {
                int row = (mt << 4) + (q << 2) + r;
                red1[row][(w << 1) + 0] = p;
                red1[row][(w << 1) + 1] = sq;
            }
        }
    __syncthreads();   // red1 visible; all waves done with a1 -> h writes safe

    // ---- apply LN1 + GELU in reg, write H' once as b64 (nibble-swapped cols) ----
    // orig col = (4w+ntl)*16 + c15  ->  col' = c15*16 + 4w + ntl (ntl contiguous)
    #pragma unroll
    for (int mt = 0; mt < 2; ++mt)
        #pragma unroll
        for (int r = 0; r < 4; ++r) {
            int row = (mt << 4) + (q << 2) + r;
            const float4 p0 = *(const float4*)&red1[row][0];
            const float4 p1 = *(const float4*)&red1[row][4];
            float p  = p0.x + p0.z + p1.x + p1.z;
            float sq = p0.y + p0.w + p1.y + p1.w;
            float mu = p * (1.0f / 256.0f);
            float rs = rsqrtf(sq * (1.0f / 256.0f) - mu * mu + LN_EPS);
            ushortx4 pk;
            #pragma unroll
            for (int ntl = 0; ntl < 4; ++ntl) {
                float y = (acc[mt][ntl][r] - mu) * rs * g1c[ntl] + t1c[ntl];
                pk[ntl] = f2bf(gelu_fast(y));
            }
            int gg = (c15 << 1) + (w >> 1);
            int addr = row * 256 + (((gg ^ (row & 7)) << 3) | ((w & 1) << 2));
            *(ushortx4*)&sm.h[addr] = pk;
        }
    __syncthreads();

    // ---------------- stage 2: wave w -> m-tile (w&1), n-tiles (w>>1)*4.. ----------------
    // A-frag read order is linear in col' (virtual k); W2 pack uses the matching k-perm.
    floatx4 acc2[4];
    #pragma unroll
    for (int j = 0; j < 4; ++j) acc2[j] = (floatx4){0.f, 0.f, 0.f, 0.f};

    const int mrow = ((w & 1) << 4) + c15;
    const int nh   = w >> 1;
    for (int s = 0; s < 8; ++s) {
        int kgrp = ((s << 2) + q) ^ (mrow & 7);
        const short8 a = *(const short8*)&sm.h[mrow * 256 + (kgrp << 3)];
        #pragma unroll
        for (int j = 0; j < 4; ++j) {
            int nt = (nh << 2) + j;
            const short8 b = *(const short8*)&W2p[((((nt << 3) + s) << 6) + lane) << 3];
            acc2[j] = __builtin_amdgcn_mfma_f32_16x16x32_bf16(a, b, acc2[j], 0, 0, 0);
        }
    }

    float b2c[4], g2c[4], t2c[4];
    #pragma unroll
    for (int j = 0; j < 4; ++j) {
        int col = (((nh << 2) + j) << 4) + c15;
        b2c[j] = b2[col]; g2c[j] = g2[col]; t2c[j] = bt2[col];
    }
    #pragma unroll
    for (int r = 0; r < 4; ++r) {
        float p = 0.f, sq = 0.f;
        #pragma unroll
        for (int j = 0; j < 4; ++j) {
            float v = acc2[j][r] + b2c[j];
            acc2[j][r] = v;
            p += v; sq += v * v;
        }
        p += __shfl_xor(p, 1);  sq += __shfl_xor(sq, 1);
        p += __shfl_xor(p, 2);  sq += __shfl_xor(sq, 2);
        p += __shfl_xor(p, 4);  sq += __shfl_xor(sq, 4);
        p += __shfl_xor(p, 8);  sq += __shfl_xor(sq, 8);
        if (c15 == 0) {
            int row = ((w & 1) << 4) + (q << 2) + r;
            red2[row][(nh << 1) + 0] = p;
            red2[row][(nh << 1) + 1] = sq;
        }
    }
    __syncthreads();

    // ---------------- epilogue: LN2 + residual store ----------------
    #pragma unroll
    for (int r = 0; r < 4; ++r) {
        int row = ((w & 1) << 4) + (q << 2) + r;
        const float4 pp = *(const float4*)&red2[row][0];
        float p  = pp.x + pp.z;
        float sq = pp.y + pp.w;
        float mu = p * (1.0f / 128.0f);
        float rs = rsqrtf(sq * (1.0f / 128.0f) - mu * mu + LN_EPS);
        int rowg = r0 + row;
        if (ROWS_TOTAL % ROWS == 0 || rowg < ROWS_TOTAL) {
            #pragma unroll
            for (int j = 0; j < 4; ++j) {
                int col = (((nh << 2) + j) << 4) + c15;
                float o = (acc2[j][r] - mu) * rs * g2c[j] + t2c[j];
                target[(size_t)rowg * DD + col] += o;
            }
        }
    }
}

extern "C" void kernel_launch(void* const* d_in, const int* in_sizes, int n_in,
                              void* d_out, int out_size, void* d_ws, size_t ws_size,
                              hipStream_t stream) {
    const float* x_in  = (const float*)d_in[0];
    const int*   ei    = (const int*)  d_in[1];
    const float* ea_in = (const float*)d_in[2];
    const float* ew1 = (const float*)d_in[3];
    const float* eb1 = (const float*)d_in[4];
    const float* eg1 = (const float*)d_in[5];
    const float* ebt1= (const float*)d_in[6];
    const float* ew2 = (const float*)d_in[7];
    const float* eb2 = (const float*)d_in[8];
    const float* eg2 = (const float*)d_in[9];
    const float* ebt2= (const float*)d_in[10];
    const float* nw1 = (const float*)d_in[11];
    const float* nb1 = (const float*)d_in[12];
    const float* ng1 = (const float*)d_in[13];
    const float* nbt1= (const float*)d_in[14];
    const float* nw2 = (const float*)d_in[15];
    const float* nb2 = (const float*)d_in[16];
    const float* ng2 = (const float*)d_in[17];
    const float* nbt2= (const float*)d_in[18];

    const int* erow = ei;
    const int* ecol = ei + NE;

    float* xbuf  = (float*)d_out;            // [NN, DD]
    float* eabuf = (float*)d_out + NN * DD;  // [NE, DD]

    // workspace layout
    unsigned short* ew1p = (unsigned short*)d_ws;
    unsigned short* ew2p = ew1p + N_EW1;
    unsigned short* nw1p = ew2p + N_EW2;
    unsigned short* nw2p = nw1p + N_NW1;
    int*   cnt    = (int*)(nw2p + N_NW2);
    int*   starts = cnt + NN;
    int*   cursor = starts + NN;
    int*   eidx   = cursor + NN;
    float* cinv   = (float*)(eidx + NE);
    float* agg    = cinv + NN;               // [NN, DD]

    hipMemcpyAsync(xbuf,  x_in,  (size_t)NN * DD * sizeof(float), hipMemcpyDeviceToDevice, stream);
    hipMemcpyAsync(eabuf, ea_in, (size_t)NE * DD * sizeof(float), hipMemcpyDeviceToDevice, stream);

    // CSR build
    hipMemsetAsync(cnt, 0, NN * sizeof(int), stream);
    hist_kernel<<<(NE + 255) / 256, 256, 0, stream>>>(ecol, cnt);
    scan_kernel<<<1, 256, 0, stream>>>(cnt, starts, cursor, cinv);
    fill_kernel<<<(NE + 255) / 256, 256, 0, stream>>>(ecol, cursor, eidx);

    // weight packing (stage-2 weights get the k-permutation)
    {
        int ntot = N_EW1 + N_EW2 + N_NW1 + N_NW2;
        pack_all<<<(ntot + 255) / 256, 256, 0, stream>>>(ew1, ew2, nw1, nw2, ew1p);
    }

    for (int i = 0; i < NL; ++i) {
        mlp_mfma<384, NE, true><<<NE / 32, 256, 0, stream>>>(
            xbuf, erow, ecol, nullptr, eabuf,
            ew1p + (size_t)i * 384 * 256, ew2p + (size_t)i * 256 * 128,
            eb1 + (size_t)i * 256, eg1 + (size_t)i * 256, ebt1 + (size_t)i * 256,
            eb2 + (size_t)i * 128, eg2 + (size_t)i * 128, ebt2 + (size_t)i * 128);
        agg_kernel<<<(NN + 3) / 4, 256, 0, stream>>>(eabuf, starts, cnt, cinv, eidx, agg);
        mlp_mfma<256, NN, false><<<(NN + 31) / 32, 256, 0, stream>>>(
            xbuf, nullptr, nullptr, agg, xbuf,
            nw1p + (size_t)i * 256 * 256, nw2p + (size_t)i * 256 * 128,
            nb1 + (size_t)i * 256, ng1 + (size_t)i * 256, nbt1 + (size_t)i * 256,
            nb2 + (size_t)i * 128, ng2 + (size_t)i * 128, nbt2 + (size_t)i * 128);
    }
}

// Round 5
// 1291.326 us; speedup vs baseline: 5.1120x; 1.1423x over previous
//
#include <hip/hip_runtime.h>
#include <hip/hip_bf16.h>
#include <math.h>

#define NN 10000
#define NE 60000
#define DD 128
#define NL 15
#define LN_EPS 1e-5f

typedef __attribute__((ext_vector_type(8))) short short8;       // 8 bf16 (MFMA A/B frag)
typedef __attribute__((ext_vector_type(4))) float floatx4;      // MFMA C/D frag

__device__ __forceinline__ unsigned short f2bf(float f) {
    unsigned u = __float_as_uint(f);
    u += 0x7fff + ((u >> 16) & 1);   // RNE
    return (unsigned short)(u >> 16);
}
// packed f32x2 -> bf16x2 (v_cvt_pk_bf16_f32 on gfx950), result as one uint
__device__ __forceinline__ unsigned bc2(float a, float b) {
    __hip_bfloat162 t = __float22bfloat162_rn(make_float2(a, b));
    return *(unsigned*)&t;
}
// gelu(y) ~= y * sigmoid(1.5957691*y + 0.0713548*y^3)
__device__ __forceinline__ float gelu_fast(float y) {
    float u = y * y;
    float s2 = y * fmaf(u, 0.07135481283f, 1.59576912161f);
    return y * __builtin_amdgcn_rcpf(1.0f + __expf(-s2));
}

// ---- pack fp32 weights [L][K][N] -> bf16 MFMA B-fragment layout ----
// dst (within layer) = (t*S + s)*512 + l*8 + j ; virtual k = 32s+8(l>>4)+j ; n=16t+(l&15)
// PERM (stage-2 weights, K=256): physical k = ((kv&15)<<4)|(kv>>4)
__device__ __forceinline__ void pack_one(const float* __restrict__ W, unsigned short* __restrict__ P,
                                         int u, int Kk, int Nk, bool perm) {
    int per_layer = Kk * Nk;
    int i = u / per_layer;
    int v0 = u - i * per_layer;
    int S = Kk >> 5;
    int t = v0 / (S * 512);
    int rem = v0 - t * (S * 512);
    int s = rem >> 9;
    int v = rem & 511;
    int l = v >> 3, j = v & 7;
    int kv = (s << 5) + ((l >> 4) << 3) + j;
    int k = perm ? (((kv & 15) << 4) | (kv >> 4)) : kv;
    int n = (t << 4) + (l & 15);
    P[u] = f2bf(W[((size_t)i * Kk + k) * Nk + n]);
}

#define N_EW1 (NL * 384 * 256)
#define N_EW2 (NL * 256 * 128)
#define N_NW1 (NL * 256 * 256)
#define N_NW2 (NL * 256 * 128)

__global__ void pack_all(const float* __restrict__ ew1, const float* __restrict__ ew2,
                         const float* __restrict__ nw1, const float* __restrict__ nw2,
                         unsigned short* __restrict__ P) {
    int tid = blockIdx.x * blockDim.x + threadIdx.x;
    if (tid < N_EW1) { pack_one(ew1, P, tid, 384, 256, false); return; }
    tid -= N_EW1;
    if (tid < N_EW2) { pack_one(ew2, P + N_EW1, tid, 256, 128, true); return; }
    tid -= N_EW2;
    if (tid < N_NW1) { pack_one(nw1, P + N_EW1 + N_EW2, tid, 256, 256, false); return; }
    tid -= N_NW1;
    if (tid < N_NW2) { pack_one(nw2, P + N_EW1 + N_EW2 + N_NW1, tid, 256, 128, true); return; }
}

// ---- CSR build (once per launch) ----
__global__ void hist_kernel(const int* __restrict__ ecol, int* __restrict__ cnt) {
    int e = blockIdx.x * blockDim.x + threadIdx.x;
    if (e < NE) atomicAdd(&cnt[ecol[e]], 1);
}

__global__ void scan_kernel(const int* __restrict__ cnt, int* __restrict__ starts,
                            int* __restrict__ cursor, float* __restrict__ cinv) {
    __shared__ int part[256];
    int t = threadIdx.x;
    const int chunk = (NN + 255) / 256;
    int lo = t * chunk;
    int hi = lo + chunk; if (hi > NN) hi = NN;
    int s = 0;
    for (int n = lo; n < hi; ++n) s += cnt[n];
    part[t] = s;
    __syncthreads();
    for (int off = 1; off < 256; off <<= 1) {
        int v = (t >= off) ? part[t - off] : 0;
        __syncthreads();
        part[t] += v;
        __syncthreads();
    }
    int base = part[t] - s;
    for (int n = lo; n < hi; ++n) {
        int c = cnt[n];
        starts[n] = base; cursor[n] = base;
        cinv[n] = 1.0f / (float)(c > 0 ? c : 1);
        base += c;
    }
}

__global__ void fill_kernel(const int* __restrict__ ecol, int* __restrict__ cursor,
                            int* __restrict__ eidx) {
    int e = blockIdx.x * blockDim.x + threadIdx.x;
    if (e < NE) {
        int slot = atomicAdd(&cursor[ecol[e]], 1);
        eidx[slot] = e;
    }
}

// ---- aggregation: one wave per node, lane covers 2 cols (coalesced 512B/edge) ----
__global__ __launch_bounds__(256)
void agg_kernel(const float* __restrict__ ea, const int* __restrict__ starts,
                const int* __restrict__ cnt, const float* __restrict__ cinv,
                const int* __restrict__ eidx, float* __restrict__ agg) {
    int n = blockIdx.x * 4 + (threadIdx.x >> 6);
    if (n >= NN) return;
    int lane = threadIdx.x & 63;
    int st = starts[n], de = cnt[n];
    float sx = 0.f, sy = 0.f;
    for (int i = 0; i < de; ++i) {
        int e = eidx[st + i];
        const float2 v = *(const float2*)&ea[(size_t)e * DD + lane * 2];
        sx += v.x; sy += v.y;
    }
    float ci = cinv[n];
    float2 o; o.x = sx * ci; o.y = sy * ci;
    *(float2*)&agg[(size_t)n * DD + lane * 2] = o;
}

// ---- fused MFMA MLP: 32 rows/block, 4 waves, single b64-granular H round-trip ----
template <int K1, int ROWS_TOTAL, bool EDGE>
__global__ __launch_bounds__(256, 4)
void mlp_mfma(const float* __restrict__ xin,
              const int* __restrict__ erow, const int* __restrict__ ecol,
              const float* __restrict__ aux,        // NODE: agg (dense fp32)
              float* __restrict__ target,           // EDGE: ea ; NODE: x
              const unsigned short* __restrict__ W1p, const unsigned short* __restrict__ W2p,
              const float* __restrict__ b1, const float* __restrict__ g1, const float* __restrict__ bt1,
              const float* __restrict__ b2, const float* __restrict__ g2, const float* __restrict__ bt2)
{
    constexpr int S1 = K1 / 32;
    constexpr int ROWS = 32;
    constexpr int NIT = K1 / 64;      // gather iterations (6 edge, 4 node)
    __shared__ union {
        unsigned short a1[ROWS * K1];     // gather tile (bf16, XOR-swizzled groups of 8)
        unsigned short h[ROWS * 256];     // stage-1 activations, nibble-swapped col layout
    } sm;
    __shared__ float red1[ROWS][8];
    __shared__ float red2[ROWS][4];

    const int tid  = threadIdx.x;
    const int lane = tid & 63;
    const int w    = tid >> 6;
    const int q    = lane >> 4;
    const int c15  = lane & 15;
    const int r0   = blockIdx.x * ROWS;

    // ---------------- gather -> a1: thread owns row r=tid>>3, col-group g=tid&7 ----------------
    {
        const int r = tid >> 3;
        const int g = tid & 7;
        const int row_g = r0 + r;
        const bool ok = (ROWS_TOTAL % ROWS == 0) || (row_g < ROWS_TOTAL);
        const float* baseA;     // cols 0..127
        const float* baseB;     // cols 128..255
        const float* baseC = nullptr;  // cols 256..383 (edge only)
        if (EDGE) {
            baseA = &xin[(size_t)erow[row_g] * DD];
            baseB = &xin[(size_t)ecol[row_g] * DD];
            baseC = &target[(size_t)row_g * DD];
        } else {
            baseA = ok ? &xin[(size_t)row_g * DD] : nullptr;
            baseB = ok ? &aux[(size_t)row_g * DD] : nullptr;
        }
        #pragma unroll
        for (int it = 0; it < NIT; ++it) {
            const int p = (g + 8 * it) << 3;        // 0..K1-8, region uniform per it
            float4 v0 = make_float4(0.f, 0.f, 0.f, 0.f);
            float4 v1 = v0;
            if (!EDGE ? ok : true) {
                const float* src;
                if (p < 128)      src = baseA + p;
                else if (p < 256) src = baseB + (p - 128);
                else              src = baseC + (p - 256);
                v0 = *(const float4*)src;
                v1 = *(const float4*)(src + 4);
            }
            int addr = r * K1 + ((((g + 8 * it) ^ (r & 7)) << 3));
            uint4 pk;
            pk.x = bc2(v0.x, v0.y); pk.y = bc2(v0.z, v0.w);
            pk.z = bc2(v1.x, v1.y); pk.w = bc2(v1.z, v1.w);
            *(uint4*)&sm.a1[addr] = pk;
        }
    }
    __syncthreads();

    // ---------------- stage 1 MFMA: wave w -> n-tiles 4w..4w+3, m-tiles 0..1 ----------------
    floatx4 acc[2][4];
    #pragma unroll
    for (int mt = 0; mt < 2; ++mt)
        #pragma unroll
        for (int ntl = 0; ntl < 4; ++ntl)
            acc[mt][ntl] = (floatx4){0.f, 0.f, 0.f, 0.f};

    #pragma unroll
    for (int s = 0; s < S1; ++s) {
        short8 af[2];
        #pragma unroll
        for (int mt = 0; mt < 2; ++mt) {
            int row  = (mt << 4) + c15;
            int kgrp = ((s << 2) + q) ^ (row & 7);
            af[mt] = *(const short8*)&sm.a1[row * K1 + (kgrp << 3)];
        }
        #pragma unroll
        for (int ntl = 0; ntl < 4; ++ntl) {
            const short8 bf = *(const short8*)&W1p[((((((w << 2) + ntl) * S1) + s) << 6) + lane) << 3];
            #pragma unroll
            for (int mt = 0; mt < 2; ++mt)
                acc[mt][ntl] = __builtin_amdgcn_mfma_f32_16x16x32_bf16(af[mt], bf, acc[mt][ntl], 0, 0, 0);
        }
    }

    // bias + in-register LN1 partial stats
    float b1c[4], g1c[4], t1c[4];
    #pragma unroll
    for (int ntl = 0; ntl < 4; ++ntl) {
        int col = (((w << 2) + ntl) << 4) + c15;
        b1c[ntl] = b1[col]; g1c[ntl] = g1[col]; t1c[ntl] = bt1[col];
    }
    #pragma unroll
    for (int mt = 0; mt < 2; ++mt)
        #pragma unroll
        for (int r = 0; r < 4; ++r) {
            float p = 0.f, sq = 0.f;
            #pragma unroll
            for (int ntl = 0; ntl < 4; ++ntl) {
                float v = acc[mt][ntl][r] + b1c[ntl];
                acc[mt][ntl][r] = v;
                p += v; sq += v * v;
            }
            p += __shfl_xor(p, 1);  sq += __shfl_xor(sq, 1);
            p += __shfl_xor(p, 2);  sq += __shfl_xor(sq, 2);
            p += __shfl_xor(p, 4);  sq += __shfl_xor(sq, 4);
            p += __shfl_xor(p, 8);  sq += __shfl_xor(sq, 8);
            if (c15 == 0) {
                int row = (mt << 4) + (q << 2) + r;
                red1[row][(w << 1) + 0] = p;
                red1[row][(w << 1) + 1] = sq;
            }
        }
    __syncthreads();   // red1 visible; all waves done with a1 -> h writes safe

    // ---- apply LN1 + GELU in reg, write H' once as b64 (nibble-swapped cols) ----
    #pragma unroll
    for (int mt = 0; mt < 2; ++mt)
        #pragma unroll
        for (int r = 0; r < 4; ++r) {
            int row = (mt << 4) + (q << 2) + r;
            const float4 p0 = *(const float4*)&red1[row][0];
            const float4 p1 = *(const float4*)&red1[row][4];
            float p  = p0.x + p0.z + p1.x + p1.z;
            float sq = p0.y + p0.w + p1.y + p1.w;
            float mu = p * (1.0f / 256.0f);
            float rs = rsqrtf(sq * (1.0f / 256.0f) - mu * mu + LN_EPS);
            float y0 = gelu_fast((acc[mt][0][r] - mu) * rs * g1c[0] + t1c[0]);
            float y1 = gelu_fast((acc[mt][1][r] - mu) * rs * g1c[1] + t1c[1]);
            float y2 = gelu_fast((acc[mt][2][r] - mu) * rs * g1c[2] + t1c[2]);
            float y3 = gelu_fast((acc[mt][3][r] - mu) * rs * g1c[3] + t1c[3]);
            uint2 hp;
            hp.x = bc2(y0, y1);
            hp.y = bc2(y2, y3);
            int gg = (c15 << 1) + (w >> 1);
            int addr = row * 256 + (((gg ^ (row & 7)) << 3) | ((w & 1) << 2));
            *(uint2*)&sm.h[addr] = hp;
        }
    __syncthreads();

    // ---------------- stage 2: wave w -> m-tile (w&1), n-tiles (w>>1)*4.. ----------------
    floatx4 acc2[4];
    #pragma unroll
    for (int j = 0; j < 4; ++j) acc2[j] = (floatx4){0.f, 0.f, 0.f, 0.f};

    const int mrow = ((w & 1) << 4) + c15;
    const int nh   = w >> 1;
    #pragma unroll
    for (int s = 0; s < 8; ++s) {
        int kgrp = ((s << 2) + q) ^ (mrow & 7);
        const short8 a = *(const short8*)&sm.h[mrow * 256 + (kgrp << 3)];
        #pragma unroll
        for (int j = 0; j < 4; ++j) {
            int nt = (nh << 2) + j;
            const short8 b = *(const short8*)&W2p[((((nt << 3) + s) << 6) + lane) << 3];
            acc2[j] = __builtin_amdgcn_mfma_f32_16x16x32_bf16(a, b, acc2[j], 0, 0, 0);
        }
    }

    float b2c[4], g2c[4], t2c[4];
    #pragma unroll
    for (int j = 0; j < 4; ++j) {
        int col = (((nh << 2) + j) << 4) + c15;
        b2c[j] = b2[col]; g2c[j] = g2[col]; t2c[j] = bt2[col];
    }
    #pragma unroll
    for (int r = 0; r < 4; ++r) {
        float p = 0.f, sq = 0.f;
        #pragma unroll
        for (int j = 0; j < 4; ++j) {
            float v = acc2[j][r] + b2c[j];
            acc2[j][r] = v;
            p += v; sq += v * v;
        }
        p += __shfl_xor(p, 1);  sq += __shfl_xor(sq, 1);
        p += __shfl_xor(p, 2);  sq += __shfl_xor(sq, 2);
        p += __shfl_xor(p, 4);  sq += __shfl_xor(sq, 4);
        p += __shfl_xor(p, 8);  sq += __shfl_xor(sq, 8);
        if (c15 == 0) {
            int row = ((w & 1) << 4) + (q << 2) + r;
            red2[row][(nh << 1) + 0] = p;
            red2[row][(nh << 1) + 1] = sq;
        }
    }
    __syncthreads();

    // ---------------- epilogue: LN2 + residual store ----------------
    #pragma unroll
    for (int r = 0; r < 4; ++r) {
        int row = ((w & 1) << 4) + (q << 2) + r;
        const float4 pp = *(const float4*)&red2[row][0];
        float p  = pp.x + pp.z;
        float sq = pp.y + pp.w;
        float mu = p * (1.0f / 128.0f);
        float rs = rsqrtf(sq * (1.0f / 128.0f) - mu * mu + LN_EPS);
        int rowg = r0 + row;
        if (ROWS_TOTAL % ROWS == 0 || rowg < ROWS_TOTAL) {
            #pragma unroll
            for (int j = 0; j < 4; ++j) {
                int col = (((nh << 2) + j) << 4) + c15;
                float o = (acc2[j][r] - mu) * rs * g2c[j] + t2c[j];
                target[(size_t)rowg * DD + col] += o;
            }
        }
    }
}

extern "C" void kernel_launch(void* const* d_in, const int* in_sizes, int n_in,
                              void* d_out, int out_size, void* d_ws, size_t ws_size,
                              hipStream_t stream) {
    const float* x_in  = (const float*)d_in[0];
    const int*   ei    = (const int*)  d_in[1];
    const float* ea_in = (const float*)d_in[2];
    const float* ew1 = (const float*)d_in[3];
    const float* eb1 = (const float*)d_in[4];
    const float* eg1 = (const float*)d_in[5];
    const float* ebt1= (const float*)d_in[6];
    const float* ew2 = (const float*)d_in[7];
    const float* eb2 = (const float*)d_in[8];
    const float* eg2 = (const float*)d_in[9];
    const float* ebt2= (const float*)d_in[10];
    const float* nw1 = (const float*)d_in[11];
    const float* nb1 = (const float*)d_in[12];
    const float* ng1 = (const float*)d_in[13];
    const float* nbt1= (const float*)d_in[14];
    const float* nw2 = (const float*)d_in[15];
    const float* nb2 = (const float*)d_in[16];
    const float* ng2 = (const float*)d_in[17];
    const float* nbt2= (const float*)d_in[18];

    const int* erow = ei;
    const int* ecol = ei + NE;

    float* xbuf  = (float*)d_out;            // [NN, DD]
    float* eabuf = (float*)d_out + NN * DD;  // [NE, DD]

    // workspace layout
    unsigned short* ew1p = (unsigned short*)d_ws;
    unsigned short* ew2p = ew1p + N_EW1;
    unsigned short* nw1p = ew2p + N_EW2;
    unsigned short* nw2p = nw1p + N_NW1;
    int*   cnt    = (int*)(nw2p + N_NW2);
    int*   starts = cnt + NN;
    int*   cursor = starts + NN;
    int*   eidx   = cursor + NN;
    float* cinv   = (float*)(eidx + NE);
    float* agg    = cinv + NN;               // [NN, DD]

    hipMemcpyAsync(xbuf,  x_in,  (size_t)NN * DD * sizeof(float), hipMemcpyDeviceToDevice, stream);
    hipMemcpyAsync(eabuf, ea_in, (size_t)NE * DD * sizeof(float), hipMemcpyDeviceToDevice, stream);

    // CSR build
    hipMemsetAsync(cnt, 0, NN * sizeof(int), stream);
    hist_kernel<<<(NE + 255) / 256, 256, 0, stream>>>(ecol, cnt);
    scan_kernel<<<1, 256, 0, stream>>>(cnt, starts, cursor, cinv);
    fill_kernel<<<(NE + 255) / 256, 256, 0, stream>>>(ecol, cursor, eidx);

    // weight packing (stage-2 weights get the k-permutation)
    {
        int ntot = N_EW1 + N_EW2 + N_NW1 + N_NW2;
        pack_all<<<(ntot + 255) / 256, 256, 0, stream>>>(ew1, ew2, nw1, nw2, ew1p);
    }

    for (int i = 0; i < NL; ++i) {
        mlp_mfma<384, NE, true><<<NE / 32, 256, 0, stream>>>(
            xbuf, erow, ecol, nullptr, eabuf,
            ew1p + (size_t)i * 384 * 256, ew2p + (size_t)i * 256 * 128,
            eb1 + (size_t)i * 256, eg1 + (size_t)i * 256, ebt1 + (size_t)i * 256,
            eb2 + (size_t)i * 128, eg2 + (size_t)i * 128, ebt2 + (size_t)i * 128);
        agg_kernel<<<(NN + 3) / 4, 256, 0, stream>>>(eabuf, starts, cnt, cinv, eidx, agg);
        mlp_mfma<256, NN, false><<<(NN + 31) / 32, 256, 0, stream>>>(
            xbuf, nullptr, nullptr, agg, xbuf,
            nw1p + (size_t)i * 256 * 256, nw2p + (size_t)i * 256 * 128,
            nb1 + (size_t)i * 256, ng1 + (size_t)i * 256, nbt1 + (size_t)i * 256,
            nb2 + (size_t)i * 128, ng2 + (size_t)i * 128, nbt2 + (size_t)i * 128);
    }
}